// Round 1
// baseline (306.891 us; speedup 1.0000x reference)
//
#include <hip/hip_runtime.h>
#include <hip/hip_bf16.h>
#include <math.h>

// Attention block: y = out_proj(causal_softmax(rope(q)·rope(k)^T)·v)
// B=2 T=2048 C=2048 Hq=32 Hkv=8 D=64. bf16 MFMA 16x16x32, fp32 accumulate.
// R6: gemm_qkv rewritten as 256x256/BK=64 8-wave 4-phase-per-K-tile schedule
// (T2 chunk-swizzle panels + T3/T4 counted vmcnt(4) + T5 setprio). LDS 128KB,
// K-half panels [buf][ks][256][32]; one panel staged per phase via
// global_load_lds; per-tile single vmcnt(4) keeps 4 loads in flight across
// the barrier (never drains to 0 mid-loop). RoPE/GQA/V-transpose epilogue
// unchanged (each wave still owns one 64-wide head column block).

typedef __attribute__((ext_vector_type(8))) short short8;
typedef __attribute__((ext_vector_type(4))) float f32x4;

#define MFMA16(a,b,c) __builtin_amdgcn_mfma_f32_16x16x32_bf16((a),(b),(c),0,0,0)
#define QSCALE 0.18033688011112043f   // (1/sqrt(64))*log2(e): exp2-domain softmax
#define NFREQ  (-13.28771237954945f / 32.0f)  // -log2(10000)/32

__device__ __forceinline__ ushort f2bf(float f) {
  union { float f; unsigned u; } x; x.f = f;
  unsigned r = x.u + 0x7fffu + ((x.u >> 16) & 1u);   // RNE
  return (ushort)(r >> 16);
}
// round-half-up packed bf16 pair (5 int ops)
__device__ __forceinline__ uint pkbf(float a, float b) {
  union { float f; unsigned u; } x, y; x.f = a; y.f = b;
  return ((x.u + 0x8000u) >> 16) | ((y.u + 0x8000u) & 0xffff0000u);
}

__device__ __forceinline__ void g2l16(const void* g, void* l) {
  __builtin_amdgcn_global_load_lds(
      (__attribute__((address_space(1))) void*)g,
      (__attribute__((address_space(3))) void*)l, 16, 0, 0);
}

// one kernel for all fp32->bf16 conversions
__global__ void cvt_all(const float* __restrict__ x,  const float* __restrict__ wq,
                        const float* __restrict__ wk, const float* __restrict__ wv,
                        const float* __restrict__ wo,
                        ushort* __restrict__ x_bf, ushort* __restrict__ wqkv,
                        ushort* __restrict__ wo_bf) {
  int i = blockIdx.x * 256 + threadIdx.x;
  const float4* src; ushort* dst; int off;
  if (i < 2097152)      { src = (const float4*)x;  dst = x_bf;             off = i; }
  else if (i < 3145728) { src = (const float4*)wq; dst = wqkv;             off = i - 2097152; }
  else if (i < 3407872) { src = (const float4*)wk; dst = wqkv + 4194304;   off = i - 3145728; }
  else if (i < 3670016) { src = (const float4*)wv; dst = wqkv + 5242880;   off = i - 3407872; }
  else                  { src = (const float4*)wo; dst = wo_bf;            off = i - 3670016; }
  float4 v = src[off];
  ushort4 o;
  o.x = f2bf(v.x); o.y = f2bf(v.y); o.z = f2bf(v.z); o.w = f2bf(v.w);
  ((ushort4*)dst)[off] = o;
}

// ---------------------------------------------------------------------------
// QKV GEMM, 256x256 tile, BK=64, 512 threads (8 waves as 2M x 4N), 4 phases
// per K-tile, fused RoPE/scatter epilogue. M=4096, N=3072, K=2048, grid(12,16).
// Column blocks: bx<8 -> q (rope+QSCALE -> qr), bx in {8,9} -> k (rope -> kr),
// bx in {10,11} -> v (transpose -> vt).
//
// LDS: As/Bs[buf][ks][256 rows][32 cols] k-half panels. Chunk swizzle: 16B
// chunk c of row r stored holding global chunk c ^ ((r>>1)&3) (same family as
// the previous kernel's, measured 0 bank conflicts). global_load_lds dest is
// linear; the swizzle is applied on the per-lane GLOBAL source address.
//
// Issue/wait ledger (per thread, 2 loads per panel; per-tile periodic):
//   phase1 (ks0,mh0): issue A-k1(t+1)   [region last read at (t-1).p3/p4]
//   phase2 (ks0,mh1): issue B-k1(t+1)
//   phase3 (ks1,mh0): issue A-k0(t+2)   [region last read at t.p1/p2]
//   phase4 (ks1,mh1): issue B-k0(t+2); s_waitcnt vmcnt(4); s_barrier
// vmcnt(4) at tile end leaves exactly k0(t+2) (4 loads) in flight and
// guarantees k0(t+1) (issued t-1.p3/p4) and k1(t+1) (issued t.p1/p2) landed.
// ---------------------------------------------------------------------------
#define PHASE(curb, ksv, mhv, LOADB, STAGE_CODE, TAIL_CODE)                       \
  {                                                                               \
    short8 af[4];                                                                 \
    _Pragma("unroll")                                                             \
    for (int mi = 0; mi < 4; ++mi)                                                \
      af[mi] = *(const short8*)(&As[curb][ksv][(wm*128 + (mhv)*64 + mi*16 + l16)*32 + rdsw]); \
    if (LOADB) {                                                                  \
      _Pragma("unroll")                                                           \
      for (int ni = 0; ni < 4; ++ni)                                              \
        bfr[ni] = *(const short8*)(&Bs[curb][ksv][(wn*64 + ni*16 + l16)*32 + rdsw]); \
    }                                                                             \
    STAGE_CODE;                                                                   \
    __builtin_amdgcn_s_barrier();                                                 \
    asm volatile("s_waitcnt lgkmcnt(0)" ::: "memory");                            \
    __builtin_amdgcn_sched_barrier(0);                                            \
    __builtin_amdgcn_s_setprio(1);                                                \
    _Pragma("unroll")                                                             \
    for (int mi = 0; mi < 4; ++mi) {                                              \
      _Pragma("unroll")                                                           \
      for (int ni = 0; ni < 4; ++ni)                                              \
        acc[(mhv)*4+mi][ni] = MFMA16(af[mi], bfr[ni], acc[(mhv)*4+mi][ni]);       \
    }                                                                             \
    __builtin_amdgcn_s_setprio(0);                                                \
    __builtin_amdgcn_sched_barrier(0);                                            \
    TAIL_CODE;                                                                    \
    __builtin_amdgcn_s_barrier();                                                 \
    __builtin_amdgcn_sched_barrier(0);                                            \
  }

__global__ __launch_bounds__(512, 2)
void gemm_qkv(const ushort* __restrict__ A, const ushort* __restrict__ Bw,
              const float* __restrict__ bq, const float* __restrict__ bk,
              const float* __restrict__ bv,
              ushort* __restrict__ qr, ushort* __restrict__ kr,
              ushort* __restrict__ vt) {
  __shared__ ushort As[2][2][8192];   // [buf][ks][256*32]
  __shared__ ushort Bs[2][2][8192];
  const int tid = threadIdx.x;
  const int wave = tid >> 6, lane = tid & 63;
  const int wm = wave >> 2, wn = wave & 3;          // 2M x 4N waves
  const int quad = lane >> 4, l16 = lane & 15;
  const int swg = (l16 >> 1) & 3;
  const int rdsw = ((quad ^ swg) * 8);
  const int m0 = blockIdx.y * 256, n0 = blockIdx.x * 256;

  f32x4 acc[8][4] = {};
  short8 bfr[4];

  // stage one k-half panel (256 rows x 32 cols) of A or B: 2 loads/thread
  auto stageA = [&](int buf, int ks, int kcol) {
#pragma unroll
    for (int i = 0; i < 2; ++i) {
      int seg = i*8 + wave;
      int p = seg*64 + lane;
      int row = p >> 2;
      int cg = (p & 3) ^ ((row >> 1) & 3);
      g2l16(A + (size_t)(m0 + row) * 2048 + kcol + cg * 8, &As[buf][ks][seg * 512]);
    }
  };
  auto stageB = [&](int buf, int ks, int kcol) {
#pragma unroll
    for (int i = 0; i < 2; ++i) {
      int seg = i*8 + wave;
      int p = seg*64 + lane;
      int row = p >> 2;
      int cg = (p & 3) ^ ((row >> 1) & 3);
      g2l16(Bw + (size_t)(n0 + row) * 2048 + kcol + cg * 8, &Bs[buf][ks][seg * 512]);
    }
  };

  // prologue: k0(t0), k1(t0), k0(t1); wait first two tiles' k0/k1 (8 of 12)
  stageA(0, 0, 0);   stageB(0, 0, 0);
  stageA(0, 1, 32);  stageB(0, 1, 32);
  stageA(1, 0, 64);  stageB(1, 0, 64);
  asm volatile("s_waitcnt vmcnt(4)" ::: "memory");
  __builtin_amdgcn_s_barrier();
  __builtin_amdgcn_sched_barrier(0);

  for (int t = 0; t < 32; ++t) {
    const int cur = t & 1;
    PHASE(cur, 0, 0, true,
          { if (t < 31) stageA(cur ^ 1, 1, t*64 + 96); },
          {});
    PHASE(cur, 0, 1, false,
          { if (t < 31) stageB(cur ^ 1, 1, t*64 + 96); },
          {});
    PHASE(cur, 1, 0, true,
          { if (t < 30) stageA(cur, 0, t*64 + 128); },
          {});
    PHASE(cur, 1, 1, false,
          { if (t < 30) stageB(cur, 0, t*64 + 128); },
          { if (t < 30) { asm volatile("s_waitcnt vmcnt(4)" ::: "memory"); }
            else        { asm volatile("s_waitcnt vmcnt(0)" ::: "memory"); } });
  }

  // ---- fused epilogue (rows: wm*128 + mi*16 + quad*4 + r; cols: wn*64 + ...) ----
  const int bb = m0 >> 11;                 // batch (uniform per block)
  const int tb = (m0 & 2047) + wm*128;     // token base for this wave
  const int bx = blockIdx.x;

  if (bx < 10) {
    // q or k: rope pairs are (acc[.][ni], acc[.][ni+2]) = features (d, d+32)
    const bool isq = bx < 8;
    const float scale = isq ? QSCALE : 1.0f;
#pragma unroll
    for (int ni = 0; ni < 2; ++ni) {
      int n = n0 + wn*64 + ni*16 + l16;
      int d = ni*16 + l16;                 // = n&63, < 32
      float bias1, bias2;
      ushort* dst;
      if (isq) {
        bias1 = bq[n]; bias2 = bq[n + 32];
        dst = qr + ((size_t)(bb*32 + (n >> 6)) * 2048) * 64 + d;
      } else {
        bias1 = bk[n - 2048]; bias2 = bk[n - 2016];
        dst = kr + ((size_t)(bb*8 + ((n >> 6) - 32)) * 2048) * 64 + d;
      }
      float invf = exp2f((float)d * NFREQ);
#pragma unroll
      for (int mi = 0; mi < 8; ++mi) {
#pragma unroll
        for (int r = 0; r < 4; ++r) {
          int t = tb + mi*16 + quad*4 + r;
          float x1 = acc[mi][ni][r]   + bias1;
          float x2 = acc[mi][ni+2][r] + bias2;
          float f = (float)t * invf;
          float sn = __sinf(f), cs = __cosf(f);
          dst[(size_t)t*64]      = f2bf((x1*cs - x2*sn) * scale);
          dst[(size_t)t*64 + 32] = f2bf((x2*cs + x1*sn) * scale);
        }
      }
    }
  } else {
    // v: write transposed vt[b][hkv][d][t]; 4 consecutive t per b64 store
#pragma unroll
    for (int ni = 0; ni < 4; ++ni) {
      int n = n0 + wn*64 + ni*16 + l16;
      int d = ni*16 + l16;                 // = n&63
      float bias = bv[n - 2560];
      ushort* dst = vt + ((size_t)(bb*8 + ((n - 2560) >> 6)) * 64 + d) * 2048;
#pragma unroll
      for (int mi = 0; mi < 8; ++mi) {
        int t = tb + mi*16 + quad*4;
        uint2 pk;
        pk.x = (uint)f2bf(acc[mi][ni][0]+bias) | ((uint)f2bf(acc[mi][ni][1]+bias) << 16);
        pk.y = (uint)f2bf(acc[mi][ni][2]+bias) | ((uint)f2bf(acc[mi][ni][3]+bias) << 16);
        *(uint2*)(dst + t) = pk;
      }
    }
  }
}

// 128x128 GEMM (output projection), BK=32, dbuf, fp32 out + bias.
__global__ __launch_bounds__(256, 3)
void gemm128(const ushort* __restrict__ A, const ushort* __restrict__ Bw,
             const float* __restrict__ b0,
             float* __restrict__ Cout, int M, int N, int K) {
  __shared__ ushort As[2][128*32];
  __shared__ ushort Bs[2][128*32];
  const int tid = threadIdx.x;
  const int wave = tid >> 6, lane = tid & 63;
  const int wm = wave >> 1, wn = wave & 1;
  const int quad = lane >> 4, l16 = lane & 15;
  const int swg = (l16 >> 1) & 3;
  const int m0 = blockIdx.y * 128, n0 = blockIdx.x * 128;

  f32x4 acc[4][4] = {};

  auto stage = [&](int buf, int k0) {
#pragma unroll
    for (int i = 0; i < 2; ++i) {
      int cbase = (i*4 + wave) * 64;
      int p = cbase + lane;
      int row = p >> 2, pcb = p & 3;
      int cl = pcb ^ ((row >> 1) & 3);
      g2l16(A  + (size_t)(m0 + row) * K + k0 + cl * 8, As[buf] + (size_t)cbase * 8);
      g2l16(Bw + (size_t)(n0 + row) * K + k0 + cl * 8, Bs[buf] + (size_t)cbase * 8);
    }
  };

  stage(0, 0);
  for (int k0 = 0; k0 < K; k0 += 32) {
    __syncthreads();
    int cur = (k0 >> 5) & 1;
    if (k0 + 32 < K) stage(cur ^ 1, k0 + 32);

    short8 af[4], bfr[4];
#pragma unroll
    for (int mi = 0; mi < 4; ++mi)
      af[mi] = *(const short8*)(As[cur] + (wm*64 + mi*16 + l16)*32 + ((quad ^ swg) * 8));
#pragma unroll
    for (int ni = 0; ni < 4; ++ni)
      bfr[ni] = *(const short8*)(Bs[cur] + (wn*64 + ni*16 + l16)*32 + ((quad ^ swg) * 8));
#pragma unroll
    for (int mi = 0; mi < 4; ++mi)
#pragma unroll
      for (int ni = 0; ni < 4; ++ni)
        acc[mi][ni] = MFMA16(af[mi], bfr[ni], acc[mi][ni]);
  }

#pragma unroll
  for (int ni = 0; ni < 4; ++ni) {
    int n = n0 + wn*64 + ni*16 + l16;
    float bias = b0[n];
#pragma unroll
    for (int mi = 0; mi < 4; ++mi) {
#pragma unroll
      for (int r = 0; r < 4; ++r) {
        int m = m0 + wm*64 + mi*16 + quad*4 + r;
        Cout[(size_t)m * N + n] = acc[mi][ni][r] + bias;
      }
    }
  }
}

// Flash attention (S^T form), causal, GQA, shift-free exp2 softmax.
__global__ __launch_bounds__(256, 4)
void attn(const ushort* __restrict__ Q, const ushort* __restrict__ Kb,
          const ushort* __restrict__ Vt, ushort* __restrict__ Y) {
  __shared__ ushort Ks[2][64*64];
  __shared__ ushort Vs[2][64*64];
  __shared__ ushort Ps[4*16*64];
  const int tid = threadIdx.x, wave = tid >> 6, lane = tid & 63;
  const int quad = lane >> 4, l16 = lane & 15;
  const int h = blockIdx.y, b = blockIdx.z;
  const int hk = h >> 2;
  const ushort* Qb = Q  + ((size_t)(b*32 + h)  * 2048) * 64;
  const ushort* Kg = Kb + ((size_t)(b*8 + hk) * 2048) * 64;
  const ushort* Vg = Vt + ((size_t)(b*8 + hk) * 64) * 2048;
  ushort* Pw = Ps + wave * 1024;
  const int sw = l16 & 7;

  auto stage = [&](int buf, int kt) {
#pragma unroll
    for (int i = 0; i < 2; ++i) {
      int cbase = (i*4 + wave) * 64;
      int p = cbase + lane;
      int row = p >> 3, pcb = p & 7;
      int cl = pcb ^ (row & 7);
      g2l16(Kg + (size_t)(kt*64 + row)*64 + cl*8, Ks[buf] + (size_t)cbase*8);
      g2l16(Vg + (size_t)row*2048 + kt*64 + cl*8, Vs[buf] + (size_t)cbase*8);
    }
  };

  for (int pass = 0; pass < 2; ++pass) {
    const int qt = pass ? (31 - blockIdx.x) : blockIdx.x;
    const int q0 = qt * 64;
    const int qrow = q0 + wave*16 + l16;
    short8 qf0 = *(const short8*)(Qb + (size_t)qrow*64 + quad*8);
    short8 qf1 = *(const short8*)(Qb + (size_t)qrow*64 + 32 + quad*8);

    f32x4 o[4] = {};
    f32x4 l4 = {0.f, 0.f, 0.f, 0.f};

    __syncthreads();            // LDS reuse across passes
    stage(0, 0);

    for (int kt = 0; kt <= qt; ++kt) {
      __syncthreads();          // drain = prefetch issued one tile ago
      int cur = kt & 1;
      if (kt < qt) stage(cur ^ 1, kt + 1);

      // S^T = K Q^T
      f32x4 s[4];
#pragma unroll
      for (int kb = 0; kb < 4; ++kb) {
        const ushort* krow = Ks[cur] + (kb*16 + l16)*64;
        short8 kf0 = *(const short8*)(krow + ((quad       ^ sw) * 8));
        short8 kf1 = *(const short8*)(krow + (((4 + quad) ^ sw) * 8));
        f32x4 z = {0.f, 0.f, 0.f, 0.f};
        z = MFMA16(kf0, qf0, z);
        s[kb] = MFMA16(kf1, qf1, z);
      }

      if (kt == qt) {           // diagonal tile causal mask
        int ql = wave*16 + l16;
#pragma unroll
        for (int kb = 0; kb < 4; ++kb) {
          int keyl = kb*16 + quad*4;
#pragma unroll
          for (int r = 0; r < 4; ++r)
            if (keyl + r > ql) s[kb][r] = -INFINITY;
        }
      }

      // shift-free: p = exp2(s); exp2(-inf)=0 handles the mask
#pragma unroll
      for (int kb = 0; kb < 4; ++kb)
#pragma unroll
        for (int r = 0; r < 4; ++r)
          s[kb][r] = __builtin_amdgcn_exp2f(s[kb][r]);

      l4 += (s[0] + s[1]) + (s[2] + s[3]);

#pragma unroll
      for (int kb = 0; kb < 4; ++kb) {
        uint2 pk;
        pk.x = pkbf(s[kb][0], s[kb][1]);
        pk.y = pkbf(s[kb][2], s[kb][3]);
        int G = (kb*2 + (quad >> 1)) ^ sw;
        *(uint2*)((char*)Pw + l16*128 + G*16 + (quad & 1)*8) = pk;
      }

      // O^T += V^T P^T
#pragma unroll
      for (int kc = 0; kc < 2; ++kc) {
        short8 pf = *(const short8*)((char*)Pw + l16*128 + (((kc*4 + quad) ^ sw) * 16));
#pragma unroll
        for (int db = 0; db < 4; ++db) {
          const ushort* vrow = Vs[cur] + (db*16 + l16)*64;
          short8 vf = *(const short8*)(vrow + (((kc*4 + quad) ^ sw) * 8));
          o[db] = MFMA16(vf, pf, o[db]);
        }
      }
    }

    float l = (l4[0] + l4[1]) + (l4[2] + l4[3]);
    l += __shfl_xor(l, 16);
    l += __shfl_xor(l, 32);
    float inv = 1.0f / l;

    int q = q0 + wave*16 + l16;
#pragma unroll
    for (int db = 0; db < 4; ++db) {
      size_t base = ((size_t)(b*2048 + q)) * 2048 + h*64 + db*16 + quad*4;
      ((uint*)Y)[base >> 1]       = pkbf(o[db][0]*inv, o[db][1]*inv);
      ((uint*)Y)[(base >> 1) + 1] = pkbf(o[db][2]*inv, o[db][3]*inv);
    }
  }
}

extern "C" void kernel_launch(void* const* d_in, const int* in_sizes, int n_in,
                              void* d_out, int out_size, void* d_ws, size_t ws_size,
                              hipStream_t stream) {
  (void)in_sizes; (void)n_in; (void)out_size; (void)ws_size;
  const float* x  = (const float*)d_in[0];
  const float* Wq = (const float*)d_in[1];
  const float* bq = (const float*)d_in[2];
  const float* Wk = (const float*)d_in[3];
  const float* bk = (const float*)d_in[4];
  const float* Wv = (const float*)d_in[5];
  const float* bv = (const float*)d_in[6];
  const float* Wo = (const float*)d_in[7];
  const float* bo = (const float*)d_in[8];
  float* out = (float*)d_out;

  ushort* ws    = (ushort*)d_ws;
  ushort* x_bf  = ws;                        // 8388608
  ushort* wqkv  = x_bf + 8388608;            // 6291456  [3072][2048]
  ushort* wo_bf = wqkv + 6291456;            // 4194304
  ushort* qr    = wo_bf + 4194304;           // 8388608  [2][32][2048][64]
  ushort* kr    = qr + 8388608;              // 2097152  [2][8][2048][64]
  ushort* vt    = kr + 2097152;              // 2097152  [2][8][64][2048]
  ushort* Y     = x_bf;                      // x_bf dead after gemm_qkv

  cvt_all<<<18432, 256, 0, stream>>>(x, Wq, Wk, Wv, Wo, x_bf, wqkv, wo_bf);
  gemm_qkv<<<dim3(12, 16), 512, 0, stream>>>(x_bf, wqkv, bq, bk, bv, qr, kr, vt);
  attn<<<dim3(16, 32, 2), 256, 0, stream>>>(qr, kr, vt, Y);
  gemm128<<<dim3(16, 32), 256, 0, stream>>>(Y, wo_bf, bo, out, 4096, 2048, 2048);
}

// Round 2
// 292.840 us; speedup vs baseline: 1.0480x; 1.0480x over previous
//
#include <hip/hip_runtime.h>
#include <hip/hip_bf16.h>
#include <math.h>

// Attention block: y = out_proj(causal_softmax(rope(q)·rope(k)^T)·v)
// B=2 T=2048 C=2048 Hq=32 Hkv=8 D=64. bf16 MFMA 16x16x32, fp32 accumulate.
// R7: revert to the 128x128/BK=32 3-blocks-per-CU structure (R6's 256x256
// 8-phase regressed: 192 blocks < 256 CUs and the counted-vmcnt pipeline
// never engaged -> per-CU rate identical to 2-phase). New in R7:
//  * gemm_qkv + gemm128: triple-buffered LDS (48 KiB, still 3 blocks/CU)
//    with prefetch distance 2, raw s_barrier + counted s_waitcnt vmcnt(4)
//    (never 0 mid-loop). Ledger: stage for step t issues during t-2
//    (lead ~1400cy > 900cy HBM); at step t outstanding=8, vmcnt(4) drains
//    exactly buf t; per-wave vmcnt BEFORE the barrier makes the whole
//    buffer valid at barrier-release. Tail: vmcnt(0) at last step only.
//  * attn: s_setprio(1) around MFMA clusters (T5; independent blocks).

typedef __attribute__((ext_vector_type(8))) short short8;
typedef __attribute__((ext_vector_type(4))) float f32x4;

#define MFMA16(a,b,c) __builtin_amdgcn_mfma_f32_16x16x32_bf16((a),(b),(c),0,0,0)
#define QSCALE 0.18033688011112043f   // (1/sqrt(64))*log2(e): exp2-domain softmax
#define NFREQ  (-13.28771237954945f / 32.0f)  // -log2(10000)/32

__device__ __forceinline__ ushort f2bf(float f) {
  union { float f; unsigned u; } x; x.f = f;
  unsigned r = x.u + 0x7fffu + ((x.u >> 16) & 1u);   // RNE
  return (ushort)(r >> 16);
}
// round-half-up packed bf16 pair (5 int ops)
__device__ __forceinline__ uint pkbf(float a, float b) {
  union { float f; unsigned u; } x, y; x.f = a; y.f = b;
  return ((x.u + 0x8000u) >> 16) | ((y.u + 0x8000u) & 0xffff0000u);
}

__device__ __forceinline__ void g2l16(const void* g, void* l) {
  __builtin_amdgcn_global_load_lds(
      (__attribute__((address_space(1))) void*)g,
      (__attribute__((address_space(3))) void*)l, 16, 0, 0);
}

// one kernel for all fp32->bf16 conversions
__global__ void cvt_all(const float* __restrict__ x,  const float* __restrict__ wq,
                        const float* __restrict__ wk, const float* __restrict__ wv,
                        const float* __restrict__ wo,
                        ushort* __restrict__ x_bf, ushort* __restrict__ wqkv,
                        ushort* __restrict__ wo_bf) {
  int i = blockIdx.x * 256 + threadIdx.x;
  const float4* src; ushort* dst; int off;
  if (i < 2097152)      { src = (const float4*)x;  dst = x_bf;             off = i; }
  else if (i < 3145728) { src = (const float4*)wq; dst = wqkv;             off = i - 2097152; }
  else if (i < 3407872) { src = (const float4*)wk; dst = wqkv + 4194304;   off = i - 3145728; }
  else if (i < 3670016) { src = (const float4*)wv; dst = wqkv + 5242880;   off = i - 3407872; }
  else                  { src = (const float4*)wo; dst = wo_bf;            off = i - 3670016; }
  float4 v = src[off];
  ushort4 o;
  o.x = f2bf(v.x); o.y = f2bf(v.y); o.z = f2bf(v.z); o.w = f2bf(v.w);
  ((ushort4*)dst)[off] = o;
}

// QKV GEMM with fused RoPE/scatter epilogue. M=4096, N=3072, K=2048,
// grid (24,32). Block col-segment: x<16 -> q (rope+QSCALE -> qr),
// x in 16..19 -> k (rope -> kr), x in 20..23 -> v (transpose -> vt).
__global__ __launch_bounds__(256, 3)
void gemm_qkv(const ushort* __restrict__ A, const ushort* __restrict__ Bw,
              const float* __restrict__ bq, const float* __restrict__ bk,
              const float* __restrict__ bv,
              ushort* __restrict__ qr, ushort* __restrict__ kr,
              ushort* __restrict__ vt) {
  const int K = 2048;
  __shared__ ushort As[3][128*32];
  __shared__ ushort Bs[3][128*32];
  const int tid = threadIdx.x;
  const int wave = tid >> 6, lane = tid & 63;
  const int wm = wave >> 1, wn = wave & 1;
  const int quad = lane >> 4, l16 = lane & 15;
  const int swg = (l16 >> 1) & 3;
  const int m0 = blockIdx.y * 128, n0 = blockIdx.x * 128;

  f32x4 acc[4][4] = {};

  auto stage = [&](int buf, int k0) {
#pragma unroll
    for (int i = 0; i < 2; ++i) {
      int cbase = (i*4 + wave) * 64;
      int p = cbase + lane;
      int row = p >> 2, pcb = p & 3;
      int cl = pcb ^ ((row >> 1) & 3);
      g2l16(A  + (size_t)(m0 + row) * K + k0 + cl * 8, As[buf] + (size_t)cbase * 8);
      g2l16(Bw + (size_t)(n0 + row) * K + k0 + cl * 8, Bs[buf] + (size_t)cbase * 8);
    }
  };

  // prologue: fill 2 of 3 buffers (distance-2 pipeline)
  stage(0, 0);
  stage(1, 32);
  int cur = 0, nxt = 2;
  for (int t = 0; t < 64; ++t) {
    // drain exactly buf[cur] (its 4 loads are the oldest outstanding)
    if (t < 63) asm volatile("s_waitcnt vmcnt(4)" ::: "memory");
    else        asm volatile("s_waitcnt vmcnt(0)" ::: "memory");
    __builtin_amdgcn_s_barrier();
    __builtin_amdgcn_sched_barrier(0);
    if (t < 62) stage(nxt, t*32 + 64);

    short8 af[4], bfr[4];
#pragma unroll
    for (int mi = 0; mi < 4; ++mi)
      af[mi] = *(const short8*)(As[cur] + (wm*64 + mi*16 + l16)*32 + ((quad ^ swg) * 8));
#pragma unroll
    for (int ni = 0; ni < 4; ++ni)
      bfr[ni] = *(const short8*)(Bs[cur] + (wn*64 + ni*16 + l16)*32 + ((quad ^ swg) * 8));
#pragma unroll
    for (int mi = 0; mi < 4; ++mi)
#pragma unroll
      for (int ni = 0; ni < 4; ++ni)
        acc[mi][ni] = MFMA16(af[mi], bfr[ni], acc[mi][ni]);

    cur = (cur == 2) ? 0 : cur + 1;
    nxt = (nxt == 2) ? 0 : nxt + 1;
  }

  // ---- fused epilogue ----
  const int bb = m0 >> 11;                 // batch (uniform per block)
  const int tb = (m0 & 2047) + wm*64;      // token base for this wave

  if (blockIdx.x < 20) {
    // q or k: rope pairs are (acc[.][ni], acc[.][ni+2]) = features (d, d+32)
    const bool isq = blockIdx.x < 16;
    const float scale = isq ? QSCALE : 1.0f;
#pragma unroll
    for (int ni = 0; ni < 2; ++ni) {
      int n = n0 + wn*64 + ni*16 + l16;
      int d = ni*16 + l16;                 // = n&63, < 32
      float bias1, bias2;
      ushort* dst;
      if (isq) {
        bias1 = bq[n]; bias2 = bq[n + 32];
        dst = qr + ((size_t)(bb*32 + (n >> 6)) * 2048) * 64 + d;
      } else {
        bias1 = bk[n - 2048]; bias2 = bk[n - 2016];
        dst = kr + ((size_t)(bb*8 + ((n >> 6) - 32)) * 2048) * 64 + d;
      }
      float invf = exp2f((float)d * NFREQ);
#pragma unroll
      for (int mi = 0; mi < 4; ++mi) {
#pragma unroll
        for (int r = 0; r < 4; ++r) {
          int t = tb + mi*16 + quad*4 + r;
          float x1 = acc[mi][ni][r]   + bias1;
          float x2 = acc[mi][ni+2][r] + bias2;
          float f = (float)t * invf;
          float sn = __sinf(f), cs = __cosf(f);
          dst[(size_t)t*64]      = f2bf((x1*cs - x2*sn) * scale);
          dst[(size_t)t*64 + 32] = f2bf((x2*cs + x1*sn) * scale);
        }
      }
    }
  } else {
    // v: write transposed vt[b][hkv][d][t]; 4 consecutive t per b64 store
#pragma unroll
    for (int ni = 0; ni < 4; ++ni) {
      int n = n0 + wn*64 + ni*16 + l16;
      int d = ni*16 + l16;                 // = n&63
      float bias = bv[n - 2560];
      ushort* dst = vt + ((size_t)(bb*8 + ((n - 2560) >> 6)) * 64 + d) * 2048;
#pragma unroll
      for (int mi = 0; mi < 4; ++mi) {
        int t = tb + mi*16 + quad*4;
        uint2 pk;
        pk.x = (uint)f2bf(acc[mi][ni][0]+bias) | ((uint)f2bf(acc[mi][ni][1]+bias) << 16);
        pk.y = (uint)f2bf(acc[mi][ni][2]+bias) | ((uint)f2bf(acc[mi][ni][3]+bias) << 16);
        *(uint2*)(dst + t) = pk;
      }
    }
  }
}

// 128x128 GEMM (output projection), BK=32, triple-buffer + counted vmcnt,
// fp32 out + bias.
__global__ __launch_bounds__(256, 3)
void gemm128(const ushort* __restrict__ A, const ushort* __restrict__ Bw,
             const float* __restrict__ b0,
             float* __restrict__ Cout, int M, int N, int K) {
  __shared__ ushort As[3][128*32];
  __shared__ ushort Bs[3][128*32];
  const int tid = threadIdx.x;
  const int wave = tid >> 6, lane = tid & 63;
  const int wm = wave >> 1, wn = wave & 1;
  const int quad = lane >> 4, l16 = lane & 15;
  const int swg = (l16 >> 1) & 3;
  const int m0 = blockIdx.y * 128, n0 = blockIdx.x * 128;

  f32x4 acc[4][4] = {};

  auto stage = [&](int buf, int k0) {
#pragma unroll
    for (int i = 0; i < 2; ++i) {
      int cbase = (i*4 + wave) * 64;
      int p = cbase + lane;
      int row = p >> 2, pcb = p & 3;
      int cl = pcb ^ ((row >> 1) & 3);
      g2l16(A  + (size_t)(m0 + row) * K + k0 + cl * 8, As[buf] + (size_t)cbase * 8);
      g2l16(Bw + (size_t)(n0 + row) * K + k0 + cl * 8, Bs[buf] + (size_t)cbase * 8);
    }
  };

  const int NT = K >> 5;
  stage(0, 0);
  stage(1, 32);
  int cur = 0, nxt = 2;
  for (int t = 0; t < NT; ++t) {
    if (t < NT-1) asm volatile("s_waitcnt vmcnt(4)" ::: "memory");
    else          asm volatile("s_waitcnt vmcnt(0)" ::: "memory");
    __builtin_amdgcn_s_barrier();
    __builtin_amdgcn_sched_barrier(0);
    if (t < NT-2) stage(nxt, t*32 + 64);

    short8 af[4], bfr[4];
#pragma unroll
    for (int mi = 0; mi < 4; ++mi)
      af[mi] = *(const short8*)(As[cur] + (wm*64 + mi*16 + l16)*32 + ((quad ^ swg) * 8));
#pragma unroll
    for (int ni = 0; ni < 4; ++ni)
      bfr[ni] = *(const short8*)(Bs[cur] + (wn*64 + ni*16 + l16)*32 + ((quad ^ swg) * 8));
#pragma unroll
    for (int mi = 0; mi < 4; ++mi)
#pragma unroll
      for (int ni = 0; ni < 4; ++ni)
        acc[mi][ni] = MFMA16(af[mi], bfr[ni], acc[mi][ni]);

    cur = (cur == 2) ? 0 : cur + 1;
    nxt = (nxt == 2) ? 0 : nxt + 1;
  }

#pragma unroll
  for (int ni = 0; ni < 4; ++ni) {
    int n = n0 + wn*64 + ni*16 + l16;
    float bias = b0[n];
#pragma unroll
    for (int mi = 0; mi < 4; ++mi) {
#pragma unroll
      for (int r = 0; r < 4; ++r) {
        int m = m0 + wm*64 + mi*16 + quad*4 + r;
        Cout[(size_t)m * N + n] = acc[mi][ni][r] + bias;
      }
    }
  }
}

// Flash attention (S^T form), causal, GQA, shift-free exp2 softmax.
__global__ __launch_bounds__(256, 4)
void attn(const ushort* __restrict__ Q, const ushort* __restrict__ Kb,
          const ushort* __restrict__ Vt, ushort* __restrict__ Y) {
  __shared__ ushort Ks[2][64*64];
  __shared__ ushort Vs[2][64*64];
  __shared__ ushort Ps[4*16*64];
  const int tid = threadIdx.x, wave = tid >> 6, lane = tid & 63;
  const int quad = lane >> 4, l16 = lane & 15;
  const int h = blockIdx.y, b = blockIdx.z;
  const int hk = h >> 2;
  const ushort* Qb = Q  + ((size_t)(b*32 + h)  * 2048) * 64;
  const ushort* Kg = Kb + ((size_t)(b*8 + hk) * 2048) * 64;
  const ushort* Vg = Vt + ((size_t)(b*8 + hk) * 64) * 2048;
  ushort* Pw = Ps + wave * 1024;
  const int sw = l16 & 7;

  auto stage = [&](int buf, int kt) {
#pragma unroll
    for (int i = 0; i < 2; ++i) {
      int cbase = (i*4 + wave) * 64;
      int p = cbase + lane;
      int row = p >> 3, pcb = p & 7;
      int cl = pcb ^ (row & 7);
      g2l16(Kg + (size_t)(kt*64 + row)*64 + cl*8, Ks[buf] + (size_t)cbase*8);
      g2l16(Vg + (size_t)row*2048 + kt*64 + cl*8, Vs[buf] + (size_t)cbase*8);
    }
  };

  for (int pass = 0; pass < 2; ++pass) {
    const int qt = pass ? (31 - blockIdx.x) : blockIdx.x;
    const int q0 = qt * 64;
    const int qrow = q0 + wave*16 + l16;
    short8 qf0 = *(const short8*)(Qb + (size_t)qrow*64 + quad*8);
    short8 qf1 = *(const short8*)(Qb + (size_t)qrow*64 + 32 + quad*8);

    f32x4 o[4] = {};
    f32x4 l4 = {0.f, 0.f, 0.f, 0.f};

    __syncthreads();            // LDS reuse across passes
    stage(0, 0);

    for (int kt = 0; kt <= qt; ++kt) {
      __syncthreads();          // drain = prefetch issued one tile ago
      int cur = kt & 1;
      if (kt < qt) stage(cur ^ 1, kt + 1);

      // S^T = K Q^T
      f32x4 s[4];
      __builtin_amdgcn_s_setprio(1);
#pragma unroll
      for (int kb = 0; kb < 4; ++kb) {
        const ushort* krow = Ks[cur] + (kb*16 + l16)*64;
        short8 kf0 = *(const short8*)(krow + ((quad       ^ sw) * 8));
        short8 kf1 = *(const short8*)(krow + (((4 + quad) ^ sw) * 8));
        f32x4 z = {0.f, 0.f, 0.f, 0.f};
        z = MFMA16(kf0, qf0, z);
        s[kb] = MFMA16(kf1, qf1, z);
      }
      __builtin_amdgcn_s_setprio(0);

      if (kt == qt) {           // diagonal tile causal mask
        int ql = wave*16 + l16;
#pragma unroll
        for (int kb = 0; kb < 4; ++kb) {
          int keyl = kb*16 + quad*4;
#pragma unroll
          for (int r = 0; r < 4; ++r)
            if (keyl + r > ql) s[kb][r] = -INFINITY;
        }
      }

      // shift-free: p = exp2(s); exp2(-inf)=0 handles the mask
#pragma unroll
      for (int kb = 0; kb < 4; ++kb)
#pragma unroll
        for (int r = 0; r < 4; ++r)
          s[kb][r] = __builtin_amdgcn_exp2f(s[kb][r]);

      l4 += (s[0] + s[1]) + (s[2] + s[3]);

#pragma unroll
      for (int kb = 0; kb < 4; ++kb) {
        uint2 pk;
        pk.x = pkbf(s[kb][0], s[kb][1]);
        pk.y = pkbf(s[kb][2], s[kb][3]);
        int G = (kb*2 + (quad >> 1)) ^ sw;
        *(uint2*)((char*)Pw + l16*128 + G*16 + (quad & 1)*8) = pk;
      }

      // O^T += V^T P^T
      __builtin_amdgcn_s_setprio(1);
#pragma unroll
      for (int kc = 0; kc < 2; ++kc) {
        short8 pf = *(const short8*)((char*)Pw + l16*128 + (((kc*4 + quad) ^ sw) * 16));
#pragma unroll
        for (int db = 0; db < 4; ++db) {
          const ushort* vrow = Vs[cur] + (db*16 + l16)*64;
          short8 vf = *(const short8*)(vrow + (((kc*4 + quad) ^ sw) * 8));
          o[db] = MFMA16(vf, pf, o[db]);
        }
      }
      __builtin_amdgcn_s_setprio(0);
    }

    float l = (l4[0] + l4[1]) + (l4[2] + l4[3]);
    l += __shfl_xor(l, 16);
    l += __shfl_xor(l, 32);
    float inv = 1.0f / l;

    int q = q0 + wave*16 + l16;
#pragma unroll
    for (int db = 0; db < 4; ++db) {
      size_t base = ((size_t)(b*2048 + q)) * 2048 + h*64 + db*16 + quad*4;
      ((uint*)Y)[base >> 1]       = pkbf(o[db][0]*inv, o[db][1]*inv);
      ((uint*)Y)[(base >> 1) + 1] = pkbf(o[db][2]*inv, o[db][3]*inv);
    }
  }
}

extern "C" void kernel_launch(void* const* d_in, const int* in_sizes, int n_in,
                              void* d_out, int out_size, void* d_ws, size_t ws_size,
                              hipStream_t stream) {
  (void)in_sizes; (void)n_in; (void)out_size; (void)ws_size;
  const float* x  = (const float*)d_in[0];
  const float* Wq = (const float*)d_in[1];
  const float* bq = (const float*)d_in[2];
  const float* Wk = (const float*)d_in[3];
  const float* bk = (const float*)d_in[4];
  const float* Wv = (const float*)d_in[5];
  const float* bv = (const float*)d_in[6];
  const float* Wo = (const float*)d_in[7];
  const float* bo = (const float*)d_in[8];
  float* out = (float*)d_out;

  ushort* ws    = (ushort*)d_ws;
  ushort* x_bf  = ws;                        // 8388608
  ushort* wqkv  = x_bf + 8388608;            // 6291456  [3072][2048]
  ushort* wo_bf = wqkv + 6291456;            // 4194304
  ushort* qr    = wo_bf + 4194304;           // 8388608  [2][32][2048][64]
  ushort* kr    = qr + 8388608;              // 2097152  [2][8][2048][64]
  ushort* vt    = kr + 2097152;              // 2097152  [2][8][64][2048]
  ushort* Y     = x_bf;                      // x_bf dead after gemm_qkv

  cvt_all<<<18432, 256, 0, stream>>>(x, Wq, Wk, Wv, Wo, x_bf, wqkv, wo_bf);
  gemm_qkv<<<dim3(24, 32), 256, 0, stream>>>(x_bf, wqkv, bq, bk, bv, qr, kr, vt);
  attn<<<dim3(16, 32, 2), 256, 0, stream>>>(qr, kr, vt, Y);
  gemm128<<<dim3(16, 32), 256, 0, stream>>>(Y, wo_bf, bo, out, 4096, 2048, 2048);
}

// Round 3
// 286.274 us; speedup vs baseline: 1.0720x; 1.0229x over previous
//
#include <hip/hip_runtime.h>
#include <hip/hip_bf16.h>
#include <math.h>

// Attention block: y = out_proj(causal_softmax(rope(q)·rope(k)^T)·v)
// B=2 T=2048 C=2048 Hq=32 Hkv=8 D=64. bf16 MFMA 16x16x32, fp32 accumulate.
// R8: GEMMs back to the round-0 structure (best measured; 3 schedules all
// hit 2.58 TF/CU so scheduling micro-variants are null) + bijective XCD
// swizzle (T1) for A-panel L2 locality. attn rewritten with 128-row Q-tiles
// (512 threads, 8 waves): halves K/V staging bytes and barriers per FLOP.

typedef __attribute__((ext_vector_type(8))) short short8;
typedef __attribute__((ext_vector_type(4))) float f32x4;

#define MFMA16(a,b,c) __builtin_amdgcn_mfma_f32_16x16x32_bf16((a),(b),(c),0,0,0)
#define QSCALE 0.18033688011112043f   // (1/sqrt(64))*log2(e): exp2-domain softmax
#define NFREQ  (-13.28771237954945f / 32.0f)  // -log2(10000)/32

__device__ __forceinline__ ushort f2bf(float f) {
  union { float f; unsigned u; } x; x.f = f;
  unsigned r = x.u + 0x7fffu + ((x.u >> 16) & 1u);   // RNE
  return (ushort)(r >> 16);
}
// round-half-up packed bf16 pair (5 int ops)
__device__ __forceinline__ uint pkbf(float a, float b) {
  union { float f; unsigned u; } x, y; x.f = a; y.f = b;
  return ((x.u + 0x8000u) >> 16) | ((y.u + 0x8000u) & 0xffff0000u);
}

__device__ __forceinline__ void g2l16(const void* g, void* l) {
  __builtin_amdgcn_global_load_lds(
      (__attribute__((address_space(1))) void*)g,
      (__attribute__((address_space(3))) void*)l, 16, 0, 0);
}

// one kernel for all fp32->bf16 conversions
__global__ void cvt_all(const float* __restrict__ x,  const float* __restrict__ wq,
                        const float* __restrict__ wk, const float* __restrict__ wv,
                        const float* __restrict__ wo,
                        ushort* __restrict__ x_bf, ushort* __restrict__ wqkv,
                        ushort* __restrict__ wo_bf) {
  int i = blockIdx.x * 256 + threadIdx.x;
  const float4* src; ushort* dst; int off;
  if (i < 2097152)      { src = (const float4*)x;  dst = x_bf;             off = i; }
  else if (i < 3145728) { src = (const float4*)wq; dst = wqkv;             off = i - 2097152; }
  else if (i < 3407872) { src = (const float4*)wk; dst = wqkv + 4194304;   off = i - 3145728; }
  else if (i < 3670016) { src = (const float4*)wv; dst = wqkv + 5242880;   off = i - 3407872; }
  else                  { src = (const float4*)wo; dst = wo_bf;            off = i - 3670016; }
  float4 v = src[off];
  ushort4 o;
  o.x = f2bf(v.x); o.y = f2bf(v.y); o.z = f2bf(v.z); o.w = f2bf(v.w);
  ((ushort4*)dst)[off] = o;
}

// QKV GEMM with fused RoPE/scatter epilogue. M=4096, N=3072, K=2048,
// grid (24,32) remapped so each XCD computes 96 contiguous tiles (4 y-rows):
// A-panels stay L2-local per XCD. Col-segment (swizzled bx): bx<16 -> q
// (rope+QSCALE -> qr), 16..19 -> k (rope -> kr), 20..23 -> v (-> vt).
__global__ __launch_bounds__(256, 3)
void gemm_qkv(const ushort* __restrict__ A, const ushort* __restrict__ Bw,
              const float* __restrict__ bq, const float* __restrict__ bk,
              const float* __restrict__ bv,
              ushort* __restrict__ qr, ushort* __restrict__ kr,
              ushort* __restrict__ vt) {
  const int K = 2048;
  __shared__ ushort As[2][128*32];
  __shared__ ushort Bs[2][128*32];
  const int tid = threadIdx.x;
  const int wave = tid >> 6, lane = tid & 63;
  const int wm = wave >> 1, wn = wave & 1;
  const int quad = lane >> 4, l16 = lane & 15;
  const int swg = (l16 >> 1) & 3;
  // bijective XCD remap: 768 blocks = 8 XCDs * 96 contiguous tiles
  int id = blockIdx.y * 24 + blockIdx.x;
  id = (id & 7) * 96 + (id >> 3);
  const int bx = id % 24, by = id / 24;
  const int m0 = by * 128, n0 = bx * 128;

  f32x4 acc[4][4] = {};

  auto stage = [&](int buf, int k0) {
#pragma unroll
    for (int i = 0; i < 2; ++i) {
      int cbase = (i*4 + wave) * 64;
      int p = cbase + lane;
      int row = p >> 2, pcb = p & 3;
      int cl = pcb ^ ((row >> 1) & 3);
      g2l16(A  + (size_t)(m0 + row) * K + k0 + cl * 8, As[buf] + (size_t)cbase * 8);
      g2l16(Bw + (size_t)(n0 + row) * K + k0 + cl * 8, Bs[buf] + (size_t)cbase * 8);
    }
  };

  stage(0, 0);
  for (int k0 = 0; k0 < K; k0 += 32) {
    __syncthreads();
    int cur = (k0 >> 5) & 1;
    if (k0 + 32 < K) stage(cur ^ 1, k0 + 32);

    short8 af[4], bfr[4];
#pragma unroll
    for (int mi = 0; mi < 4; ++mi)
      af[mi] = *(const short8*)(As[cur] + (wm*64 + mi*16 + l16)*32 + ((quad ^ swg) * 8));
#pragma unroll
    for (int ni = 0; ni < 4; ++ni)
      bfr[ni] = *(const short8*)(Bs[cur] + (wn*64 + ni*16 + l16)*32 + ((quad ^ swg) * 8));
#pragma unroll
    for (int mi = 0; mi < 4; ++mi)
#pragma unroll
      for (int ni = 0; ni < 4; ++ni)
        acc[mi][ni] = MFMA16(af[mi], bfr[ni], acc[mi][ni]);
  }

  // ---- fused epilogue ----
  const int bb = m0 >> 11;                 // batch (uniform per block)
  const int tb = (m0 & 2047) + wm*64;      // token base for this wave

  if (bx < 20) {
    // q or k: rope pairs are (acc[.][ni], acc[.][ni+2]) = features (d, d+32)
    const bool isq = bx < 16;
    const float scale = isq ? QSCALE : 1.0f;
#pragma unroll
    for (int ni = 0; ni < 2; ++ni) {
      int n = n0 + wn*64 + ni*16 + l16;
      int d = ni*16 + l16;                 // = n&63, < 32
      float bias1, bias2;
      ushort* dst;
      if (isq) {
        bias1 = bq[n]; bias2 = bq[n + 32];
        dst = qr + ((size_t)(bb*32 + (n >> 6)) * 2048) * 64 + d;
      } else {
        bias1 = bk[n - 2048]; bias2 = bk[n - 2016];
        dst = kr + ((size_t)(bb*8 + ((n >> 6) - 32)) * 2048) * 64 + d;
      }
      float invf = exp2f((float)d * NFREQ);
#pragma unroll
      for (int mi = 0; mi < 4; ++mi) {
#pragma unroll
        for (int r = 0; r < 4; ++r) {
          int t = tb + mi*16 + quad*4 + r;
          float x1 = acc[mi][ni][r]   + bias1;
          float x2 = acc[mi][ni+2][r] + bias2;
          float f = (float)t * invf;
          float sn = __sinf(f), cs = __cosf(f);
          dst[(size_t)t*64]      = f2bf((x1*cs - x2*sn) * scale);
          dst[(size_t)t*64 + 32] = f2bf((x2*cs + x1*sn) * scale);
        }
      }
    }
  } else {
    // v: write transposed vt[b][hkv][d][t]; 4 consecutive t per b64 store
#pragma unroll
    for (int ni = 0; ni < 4; ++ni) {
      int n = n0 + wn*64 + ni*16 + l16;
      int d = ni*16 + l16;                 // = n&63
      float bias = bv[n - 2560];
      ushort* dst = vt + ((size_t)(bb*8 + ((n - 2560) >> 6)) * 64 + d) * 2048;
#pragma unroll
      for (int mi = 0; mi < 4; ++mi) {
        int t = tb + mi*16 + quad*4;
        uint2 pk;
        pk.x = (uint)f2bf(acc[mi][ni][0]+bias) | ((uint)f2bf(acc[mi][ni][1]+bias) << 16);
        pk.y = (uint)f2bf(acc[mi][ni][2]+bias) | ((uint)f2bf(acc[mi][ni][3]+bias) << 16);
        *(uint2*)(dst + t) = pk;
      }
    }
  }
}

// 128x128 GEMM (output projection), BK=32, dbuf, fp32 out + bias.
// XCD remap: 512 blocks = 8 * 64 contiguous tiles.
__global__ __launch_bounds__(256, 3)
void gemm128(const ushort* __restrict__ A, const ushort* __restrict__ Bw,
             const float* __restrict__ b0,
             float* __restrict__ Cout, int M, int N, int K) {
  __shared__ ushort As[2][128*32];
  __shared__ ushort Bs[2][128*32];
  const int tid = threadIdx.x;
  const int wave = tid >> 6, lane = tid & 63;
  const int wm = wave >> 1, wn = wave & 1;
  const int quad = lane >> 4, l16 = lane & 15;
  const int swg = (l16 >> 1) & 3;
  int id = blockIdx.y * 16 + blockIdx.x;
  id = (id & 7) * 64 + (id >> 3);
  const int m0 = (id / 16) * 128, n0 = (id % 16) * 128;

  f32x4 acc[4][4] = {};

  auto stage = [&](int buf, int k0) {
#pragma unroll
    for (int i = 0; i < 2; ++i) {
      int cbase = (i*4 + wave) * 64;
      int p = cbase + lane;
      int row = p >> 2, pcb = p & 3;
      int cl = pcb ^ ((row >> 1) & 3);
      g2l16(A  + (size_t)(m0 + row) * K + k0 + cl * 8, As[buf] + (size_t)cbase * 8);
      g2l16(Bw + (size_t)(n0 + row) * K + k0 + cl * 8, Bs[buf] + (size_t)cbase * 8);
    }
  };

  stage(0, 0);
  for (int k0 = 0; k0 < K; k0 += 32) {
    __syncthreads();
    int cur = (k0 >> 5) & 1;
    if (k0 + 32 < K) stage(cur ^ 1, k0 + 32);

    short8 af[4], bfr[4];
#pragma unroll
    for (int mi = 0; mi < 4; ++mi)
      af[mi] = *(const short8*)(As[cur] + (wm*64 + mi*16 + l16)*32 + ((quad ^ swg) * 8));
#pragma unroll
    for (int ni = 0; ni < 4; ++ni)
      bfr[ni] = *(const short8*)(Bs[cur] + (wn*64 + ni*16 + l16)*32 + ((quad ^ swg) * 8));
#pragma unroll
    for (int mi = 0; mi < 4; ++mi)
#pragma unroll
      for (int ni = 0; ni < 4; ++ni)
        acc[mi][ni] = MFMA16(af[mi], bfr[ni], acc[mi][ni]);
  }

#pragma unroll
  for (int ni = 0; ni < 4; ++ni) {
    int n = n0 + wn*64 + ni*16 + l16;
    float bias = b0[n];
#pragma unroll
    for (int mi = 0; mi < 4; ++mi) {
#pragma unroll
      for (int r = 0; r < 4; ++r) {
        int m = m0 + wm*64 + mi*16 + quad*4 + r;
        Cout[(size_t)m * N + n] = acc[mi][ni][r] + bias;
      }
    }
  }
}

// Flash attention (S^T form), causal, GQA, shift-free exp2 softmax.
// R8: 128-row Q-tiles, 512 threads (8 waves, one 16-row group each).
// K/V staged once per 128 q-rows (was 64): staging bytes + barriers per
// FLOP halved. Diagonal band spans 2 kt-tiles; per-lane global mask.
__global__ __launch_bounds__(512, 4)
void attn(const ushort* __restrict__ Q, const ushort* __restrict__ Kb,
          const ushort* __restrict__ Vt, ushort* __restrict__ Y) {
  __shared__ ushort Ks[2][64*64];
  __shared__ ushort Vs[2][64*64];
  __shared__ ushort Ps[8*16*64];
  const int tid = threadIdx.x, wave = tid >> 6, lane = tid & 63;
  const int quad = lane >> 4, l16 = lane & 15;
  const int h = blockIdx.y, b = blockIdx.z;
  const int hk = h >> 2;
  const ushort* Qb = Q  + ((size_t)(b*32 + h)  * 2048) * 64;
  const ushort* Kg = Kb + ((size_t)(b*8 + hk) * 2048) * 64;
  const ushort* Vg = Vt + ((size_t)(b*8 + hk) * 64) * 2048;
  ushort* Pw = Ps + wave * 1024;
  const int sw = l16 & 7;

  // one K-row-chunk + one V-row-chunk per thread (512 threads = 8KB tile)
  auto stage = [&](int buf, int kt) {
    int p = tid;
    int row = p >> 3, pcb = p & 7;
    int cl = pcb ^ (row & 7);
    g2l16(Kg + (size_t)(kt*64 + row)*64 + cl*8, Ks[buf] + wave*512);
    g2l16(Vg + (size_t)row*2048 + kt*64 + cl*8, Vs[buf] + wave*512);
  };

  for (int pass = 0; pass < 2; ++pass) {
    const int qt = pass ? (15 - blockIdx.x) : blockIdx.x;   // pair (qt, 15-qt)
    const int q0 = qt * 128;
    const int qrow = q0 + wave*16 + l16;
    short8 qf0 = *(const short8*)(Qb + (size_t)qrow*64 + quad*8);
    short8 qf1 = *(const short8*)(Qb + (size_t)qrow*64 + 32 + quad*8);

    f32x4 o[4] = {};
    f32x4 l4 = {0.f, 0.f, 0.f, 0.f};

    __syncthreads();            // LDS reuse across passes
    stage(0, 0);

    const int ktmax = qt*2 + 1;
    for (int kt = 0; kt <= ktmax; ++kt) {
      __syncthreads();          // drain = prefetch issued one tile ago
      int cur = kt & 1;
      if (kt < ktmax) stage(cur ^ 1, kt + 1);

      // S^T = K Q^T
      f32x4 s[4];
      __builtin_amdgcn_s_setprio(1);
#pragma unroll
      for (int kb = 0; kb < 4; ++kb) {
        const ushort* krow = Ks[cur] + (kb*16 + l16)*64;
        short8 kf0 = *(const short8*)(krow + ((quad       ^ sw) * 8));
        short8 kf1 = *(const short8*)(krow + (((4 + quad) ^ sw) * 8));
        f32x4 z = {0.f, 0.f, 0.f, 0.f};
        z = MFMA16(kf0, qf0, z);
        s[kb] = MFMA16(kf1, qf1, z);
      }
      __builtin_amdgcn_s_setprio(0);

      if (kt >= qt*2) {          // diagonal band causal mask (global rows/keys)
        int ql = q0 + wave*16 + l16;
#pragma unroll
        for (int kb = 0; kb < 4; ++kb) {
          int key = kt*64 + kb*16 + quad*4;
#pragma unroll
          for (int r = 0; r < 4; ++r)
            if (key + r > ql) s[kb][r] = -INFINITY;
        }
      }

      // shift-free: p = exp2(s); exp2(-inf)=0 handles the mask
#pragma unroll
      for (int kb = 0; kb < 4; ++kb)
#pragma unroll
        for (int r = 0; r < 4; ++r)
          s[kb][r] = __builtin_amdgcn_exp2f(s[kb][r]);

      l4 += (s[0] + s[1]) + (s[2] + s[3]);

#pragma unroll
      for (int kb = 0; kb < 4; ++kb) {
        uint2 pk;
        pk.x = pkbf(s[kb][0], s[kb][1]);
        pk.y = pkbf(s[kb][2], s[kb][3]);
        int G = (kb*2 + (quad >> 1)) ^ sw;
        *(uint2*)((char*)Pw + l16*128 + G*16 + (quad & 1)*8) = pk;
      }

      // O^T += V^T P^T
      __builtin_amdgcn_s_setprio(1);
#pragma unroll
      for (int kc = 0; kc < 2; ++kc) {
        short8 pf = *(const short8*)((char*)Pw + l16*128 + (((kc*4 + quad) ^ sw) * 16));
#pragma unroll
        for (int db = 0; db < 4; ++db) {
          const ushort* vrow = Vs[cur] + (db*16 + l16)*64;
          short8 vf = *(const short8*)(vrow + (((kc*4 + quad) ^ sw) * 8));
          o[db] = MFMA16(vf, pf, o[db]);
        }
      }
      __builtin_amdgcn_s_setprio(0);
    }

    float l = (l4[0] + l4[1]) + (l4[2] + l4[3]);
    l += __shfl_xor(l, 16);
    l += __shfl_xor(l, 32);
    float inv = 1.0f / l;

    int q = q0 + wave*16 + l16;
#pragma unroll
    for (int db = 0; db < 4; ++db) {
      size_t base = ((size_t)(b*2048 + q)) * 2048 + h*64 + db*16 + quad*4;
      ((uint*)Y)[base >> 1]       = pkbf(o[db][0]*inv, o[db][1]*inv);
      ((uint*)Y)[(base >> 1) + 1] = pkbf(o[db][2]*inv, o[db][3]*inv);
    }
  }
}

extern "C" void kernel_launch(void* const* d_in, const int* in_sizes, int n_in,
                              void* d_out, int out_size, void* d_ws, size_t ws_size,
                              hipStream_t stream) {
  (void)in_sizes; (void)n_in; (void)out_size; (void)ws_size;
  const float* x  = (const float*)d_in[0];
  const float* Wq = (const float*)d_in[1];
  const float* bq = (const float*)d_in[2];
  const float* Wk = (const float*)d_in[3];
  const float* bk = (const float*)d_in[4];
  const float* Wv = (const float*)d_in[5];
  const float* bv = (const float*)d_in[6];
  const float* Wo = (const float*)d_in[7];
  const float* bo = (const float*)d_in[8];
  float* out = (float*)d_out;

  ushort* ws    = (ushort*)d_ws;
  ushort* x_bf  = ws;                        // 8388608
  ushort* wqkv  = x_bf + 8388608;            // 6291456  [3072][2048]
  ushort* wo_bf = wqkv + 6291456;            // 4194304
  ushort* qr    = wo_bf + 4194304;           // 8388608  [2][32][2048][64]
  ushort* kr    = qr + 8388608;              // 2097152  [2][8][2048][64]
  ushort* vt    = kr + 2097152;              // 2097152  [2][8][64][2048]
  ushort* Y     = x_bf;                      // x_bf dead after gemm_qkv

  cvt_all<<<18432, 256, 0, stream>>>(x, Wq, Wk, Wv, Wo, x_bf, wqkv, wo_bf);
  gemm_qkv<<<dim3(24, 32), 256, 0, stream>>>(x_bf, wqkv, bq, bk, bv, qr, kr, vt);
  attn<<<dim3(8, 32, 2), 512, 0, stream>>>(qr, kr, vt, Y);
  gemm128<<<dim3(16, 32), 256, 0, stream>>>(Y, wo_bf, bo, out, 4096, 2048, 2048);
}